// Round 7
// baseline (253.383 us; speedup 1.0000x reference)
//
#include <hip/hip_runtime.h>

#define D 640
#define HID 64
#define NITER 64
#define ROWS 8           // rows per block; each of 4 waves owns 2 rows
#define BLOCK 256

typedef float v2f __attribute__((ext_vector_type(2)));

// ---- DPP wave64 reductions (VALU pipe only) ----
#define DPP_ADD_STEP(v, ctrl, rmask)                                          \
    v += __builtin_bit_cast(float, __builtin_amdgcn_update_dpp(               \
             0, __builtin_bit_cast(int, v), ctrl, rmask, 0xf, true))
#define DPP_MAX_STEP(v, ctrl, rmask)                                          \
    v = fmaxf(v, __builtin_bit_cast(float, __builtin_amdgcn_update_dpp(       \
             __builtin_bit_cast(int, v), __builtin_bit_cast(int, v),          \
             ctrl, rmask, 0xf, false)))

// Two interleaved reduce chains (rows A and B) -> 2x ILP on the serial path.
__device__ __forceinline__ void wave_sum_dpp2(float& a, float& b) {
    DPP_ADD_STEP(a, 0x111, 0xf);  DPP_ADD_STEP(b, 0x111, 0xf);
    DPP_ADD_STEP(a, 0x112, 0xf);  DPP_ADD_STEP(b, 0x112, 0xf);
    DPP_ADD_STEP(a, 0x114, 0xf);  DPP_ADD_STEP(b, 0x114, 0xf);
    DPP_ADD_STEP(a, 0x118, 0xf);  DPP_ADD_STEP(b, 0x118, 0xf);
    DPP_ADD_STEP(a, 0x142, 0xa);  DPP_ADD_STEP(b, 0x142, 0xa);
    DPP_ADD_STEP(a, 0x143, 0xc);  DPP_ADD_STEP(b, 0x143, 0xc);
    a = __builtin_bit_cast(float,
        __builtin_amdgcn_readlane(__builtin_bit_cast(int, a), 63));
    b = __builtin_bit_cast(float,
        __builtin_amdgcn_readlane(__builtin_bit_cast(int, b), 63));
}
__device__ __forceinline__ void wave_max_dpp2(float& a, float& b) {
    DPP_MAX_STEP(a, 0x111, 0xf);  DPP_MAX_STEP(b, 0x111, 0xf);
    DPP_MAX_STEP(a, 0x112, 0xf);  DPP_MAX_STEP(b, 0x112, 0xf);
    DPP_MAX_STEP(a, 0x114, 0xf);  DPP_MAX_STEP(b, 0x114, 0xf);
    DPP_MAX_STEP(a, 0x118, 0xf);  DPP_MAX_STEP(b, 0x118, 0xf);
    DPP_MAX_STEP(a, 0x142, 0xa);  DPP_MAX_STEP(b, 0x142, 0xa);
    DPP_MAX_STEP(a, 0x143, 0xc);  DPP_MAX_STEP(b, 0x143, 0xc);
    a = __builtin_bit_cast(float,
        __builtin_amdgcn_readlane(__builtin_bit_cast(int, a), 63));
    b = __builtin_bit_cast(float,
        __builtin_amdgcn_readlane(__builtin_bit_cast(int, b), 63));
}

// One recurrence step for one v2f unit (R1/R2 branchy math, unchanged).
__device__ __forceinline__ void unit_step(v2f& e2u, float rs, float a, float b,
                                          float thr, v2f& ns) {
    const v2f K1 = {1.0f, 1.0f};
    const v2f P4 = {-0.0395668f, -0.0395668f};
    const v2f P3 = {-0.0583090f, -0.0583090f};
    const v2f P2 = {-0.1020408f, -0.1020408f};
    const v2f P1 = {-0.2857143f, -0.2857143f};
    v2f e = e2u;
    if (__builtin_expect(__any(fmaxf(e.x, e.y) > thr), 0)) {
        v2f rsv = {rs, rs};
        v2f y  = e * rsv;
        v2f f  = K1 - y;
        v2f f2 = f * f, f4 = f2 * f2, f8 = f4 * f4;
        v2f f14 = (f8 * f4) * f2;             // even powers: >= 0
        v2f p = __builtin_elementwise_fma(P4, y, P3);
        p = __builtin_elementwise_fma(p, y, P2);
        p = __builtin_elementwise_fma(p, y, P1);
        p = __builtin_elementwise_fma(p, y, K1);
        e *= f14 * p;
    } else {
        v2f av = {a, a}, bv = {b, b};
        v2f p = __builtin_elementwise_fma(bv, e, av);
        p = __builtin_elementwise_fma(p, e, K1);
        e *= p;
    }
    e2u = e;
    ns += e;
}

// Identical Phase-B loop body for probe copy and real run (same codegen).
#define PHASE_B_ITER_LOOP(EA, EB, SA, SB)                                   \
    for (int it = 0; it < NITER; ++it) {                                    \
        float sA = SA.x + SA.y;                                             \
        float sB = SB.x + SB.y;                                             \
        wave_sum_dpp2(sA, sB);                                              \
        float rsA = __builtin_amdgcn_rcpf(sA);                              \
        float rsB = __builtin_amdgcn_rcpf(sB);                              \
        float aA = -14.2857143f * rsA, bA = (94.8979592f * rsA) * rsA;      \
        float aB = -14.2857143f * rsB, bB = (94.8979592f * rsB) * rsB;      \
        float thrA = 0.02f * sA, thrB = 0.02f * sB;                         \
        v2f nsA = {0.f, 0.f}, nsB = {0.f, 0.f};                             \
        _Pragma("unroll")                                                   \
        for (int u = 0; u < 5; ++u) {                                       \
            unit_step(EA[u], rsA, aA, bA, thrA, nsA);                       \
            unit_step(EB[u], rsB, aB, bB, thrB, nsB);                       \
        }                                                                   \
        SA = nsA; SB = nsB;                                                 \
    }

// 4 blocks/CU (16 waves/CU); VGPR cap 128.
__global__ __launch_bounds__(BLOCK, 4) void dimmask_kernel(
    const float* __restrict__ x, const float* __restrict__ W1,
    const float* __restrict__ b1, const float* __restrict__ W2,
    const float* __restrict__ b2, float* __restrict__ out)
{
    constexpr float INV_T = 1.0f / 0.07f;
    constexpr float LOG2E = 1.4426950408889634f;
    constexpr float TEMP  = 0.07f;

    __shared__ float lds_a[ROWS][D];          // x rows, then ht
    __shared__ float lds_part[4][ROWS][HID];
    __shared__ float lds_hid[ROWS][HID];

    const int tid  = threadIdx.x;
    const int row0 = blockIdx.x * ROWS;

    // ---- stage x rows into LDS (coalesced float4) ----
    {
        const float4* xv  = (const float4*)(x + (size_t)row0 * D);
        float4*       lxv = (float4*)(&lds_a[0][0]);
        for (int i = tid; i < ROWS * D / 4; i += BLOCK) lxv[i] = xv[i];
    }
    __syncthreads();

    // ---- GEMM1: hid[r][k] = relu(sum_t x[r][t]*W1[t][k] + b1[k]) ----
    {
        const int k = tid & 63, c = tid >> 6;
        float acc[ROWS];
#pragma unroll
        for (int r = 0; r < ROWS; ++r) acc[r] = 0.f;
        const int q0 = c * 40;                 // float4 index base (c*160/4)
#pragma unroll 2
        for (int q = q0; q < q0 + 40; ++q) {
            const int tb = q * 4;
            float w0 = W1[(tb + 0) * HID + k];
            float w1 = W1[(tb + 1) * HID + k];
            float w2 = W1[(tb + 2) * HID + k];
            float w3 = W1[(tb + 3) * HID + k];
#pragma unroll
            for (int r = 0; r < ROWS; ++r) {
                float4 xa = ((const float4*)&lds_a[r][0])[q];
                acc[r] += xa.x * w0 + xa.y * w1 + xa.z * w2 + xa.w * w3;
            }
        }
#pragma unroll
        for (int r = 0; r < ROWS; ++r) lds_part[c][r][k] = acc[r];
    }
    __syncthreads();
    for (int idx = tid; idx < ROWS * HID; idx += BLOCK) {
        const int r = idx >> 6, k = idx & 63;
        float s = lds_part[0][r][k] + lds_part[1][r][k]
                + lds_part[2][r][k] + lds_part[3][r][k] + b1[k];
        lds_hid[r][k] = fmaxf(s, 0.f);
    }
    __syncthreads();

    // ---- GEMM2: ht[r][j] = -h*log2e/T over dead x in lds_a ----
    for (int j = tid; j < D; j += BLOCK) {
        float acc[ROWS];
#pragma unroll
        for (int r = 0; r < ROWS; ++r) acc[r] = 0.f;
#pragma unroll 2
        for (int k4 = 0; k4 < HID / 4; ++k4) {
            const int kb = k4 * 4;
            float w0 = W2[(kb + 0) * D + j];
            float w1 = W2[(kb + 1) * D + j];
            float w2 = W2[(kb + 2) * D + j];
            float w3 = W2[(kb + 3) * D + j];
#pragma unroll
            for (int r = 0; r < ROWS; ++r) {
                float4 hh = ((const float4*)&lds_hid[r][0])[k4];
                acc[r] += hh.x * w0 + hh.y * w1 + hh.z * w2 + hh.w * w3;
            }
        }
        float bb = b2[j];
#pragma unroll
        for (int r = 0; r < ROWS; ++r)
            lds_a[r][j] = -(acc[r] + bb) * (LOG2E * INV_T);
    }
    __syncthreads();

    // ---- Phase B: one wave per TWO rows; packed f32 e-domain recurrence ----
    const int w = tid >> 6, l = tid & 63;
    const int rA = 2 * w, rB = 2 * w + 1;
    v2f eA[5], eB[5];
    float hmaxA, hmaxB;
    {
        float htA[10], htB[10];
        float ha = -3.0e38f, hb = -3.0e38f;
#pragma unroll
        for (int u = 0; u < 10; ++u) {
            htA[u] = lds_a[rA][l + 64 * u];
            htB[u] = lds_a[rB][l + 64 * u];
            ha = fmaxf(ha, htA[u]);
            hb = fmaxf(hb, htB[u]);
        }
        wave_max_dpp2(ha, hb);
        hmaxA = ha; hmaxB = hb;
#pragma unroll
        for (int u = 0; u < 5; ++u) {
            eA[u].x = __builtin_amdgcn_exp2f(fmaxf(htA[2 * u]     - ha, -80.f));
            eA[u].y = __builtin_amdgcn_exp2f(fmaxf(htA[2 * u + 1] - ha, -80.f));
            eB[u].x = __builtin_amdgcn_exp2f(fmaxf(htB[2 * u]     - hb, -80.f));
            eB[u].y = __builtin_amdgcn_exp2f(fmaxf(htB[2 * u + 1] - hb, -80.f));
        }
    }

    v2f saccA = (eA[0] + eA[1]) + ((eA[2] + eA[3]) + eA[4]);
    v2f saccB = (eB[0] + eB[1]) + ((eB[2] + eB[3]) + eB[4]);

    // ==== ATTRIBUTION PROBE: throwaway duplicate of Phase B ====
    // Runs the identical 64-iteration loop on a copy of the state; the
    // asm sink keeps the whole dependency web live (no DCE) at zero cost.
    // dur delta vs the 129-us baseline == Phase B's true cost.
    {
        v2f tA[5], tB[5];
#pragma unroll
        for (int u = 0; u < 5; ++u) { tA[u] = eA[u]; tB[u] = eB[u]; }
        v2f tsA = saccA, tsB = saccB;
        PHASE_B_ITER_LOOP(tA, tB, tsA, tsB);
        asm volatile("" :: "v"(tsA.x), "v"(tsA.y), "v"(tsB.x), "v"(tsB.y));
    }

    // ==== real Phase B ====
    PHASE_B_ITER_LOOP(eA, eB, saccA, saccB);

    // ---- epilogue: m = (e/E)^T = exp2(T*(log2(e) - c)), c = clamp(ht-hmax) ----
#pragma unroll
    for (int pr = 0; pr < 2; ++pr) {
        const int r = (pr == 0) ? rA : rB;
        const float hm = (pr == 0) ? hmaxA : hmaxB;
        v2f* e2 = (pr == 0) ? eA : eB;
        const float* xrow = x + (size_t)(row0 + r) * D;
        float* orow = out + (size_t)(row0 + r) * D;
#pragma unroll
        for (int u = 0; u < 5; ++u) {
            const int j0 = l + 128 * u, j1 = j0 + 64;
            float c0 = fmaxf(lds_a[r][j0] - hm, -80.f);
            float c1 = fmaxf(lds_a[r][j1] - hm, -80.f);
            float m0 = __builtin_amdgcn_exp2f(
                TEMP * (__builtin_amdgcn_logf(e2[u].x) - c0));
            float m1 = __builtin_amdgcn_exp2f(
                TEMP * (__builtin_amdgcn_logf(e2[u].y) - c1));
            orow[j0] = m0 * xrow[j0];
            orow[j1] = m1 * xrow[j1];
        }
    }
}

extern "C" void kernel_launch(void* const* d_in, const int* in_sizes, int n_in,
                              void* d_out, int out_size, void* d_ws, size_t ws_size,
                              hipStream_t stream) {
    const float* x  = (const float*)d_in[0];
    const float* W1 = (const float*)d_in[1];
    const float* b1 = (const float*)d_in[2];
    const float* W2 = (const float*)d_in[3];
    const float* b2 = (const float*)d_in[4];
    float* out = (float*)d_out;

    const int B = in_sizes[0] / D;            // 8192
    dim3 grid(B / ROWS), block(BLOCK);
    hipLaunchKernelGGL(dimmask_kernel, grid, block, 0, stream, x, W1, b1, W2, b2, out);
}

// Round 8
// 182.683 us; speedup vs baseline: 1.3870x; 1.3870x over previous
//
#include <hip/hip_runtime.h>

#define D 640
#define HID 64
#define NITER 64
#define ROWS 8           // rows per block; each of 4 waves owns 2 rows
#define BLOCK 256

typedef float v2f __attribute__((ext_vector_type(2)));

// ---- DPP wave64 reductions (VALU pipe only) ----
#define DPP_ADD_STEP(v, ctrl, rmask)                                          \
    v += __builtin_bit_cast(float, __builtin_amdgcn_update_dpp(               \
             0, __builtin_bit_cast(int, v), ctrl, rmask, 0xf, true))
#define DPP_MAX_STEP(v, ctrl, rmask)                                          \
    v = fmaxf(v, __builtin_bit_cast(float, __builtin_amdgcn_update_dpp(       \
             __builtin_bit_cast(int, v), __builtin_bit_cast(int, v),          \
             ctrl, rmask, 0xf, false)))

// Two interleaved reduce chains (rows A and B) -> 2x ILP on the serial path.
__device__ __forceinline__ void wave_sum_dpp2(float& a, float& b) {
    DPP_ADD_STEP(a, 0x111, 0xf);  DPP_ADD_STEP(b, 0x111, 0xf);
    DPP_ADD_STEP(a, 0x112, 0xf);  DPP_ADD_STEP(b, 0x112, 0xf);
    DPP_ADD_STEP(a, 0x114, 0xf);  DPP_ADD_STEP(b, 0x114, 0xf);
    DPP_ADD_STEP(a, 0x118, 0xf);  DPP_ADD_STEP(b, 0x118, 0xf);
    DPP_ADD_STEP(a, 0x142, 0xa);  DPP_ADD_STEP(b, 0x142, 0xa);
    DPP_ADD_STEP(a, 0x143, 0xc);  DPP_ADD_STEP(b, 0x143, 0xc);
    a = __builtin_bit_cast(float,
        __builtin_amdgcn_readlane(__builtin_bit_cast(int, a), 63));
    b = __builtin_bit_cast(float,
        __builtin_amdgcn_readlane(__builtin_bit_cast(int, b), 63));
}
__device__ __forceinline__ void wave_max_dpp2(float& a, float& b) {
    DPP_MAX_STEP(a, 0x111, 0xf);  DPP_MAX_STEP(b, 0x111, 0xf);
    DPP_MAX_STEP(a, 0x112, 0xf);  DPP_MAX_STEP(b, 0x112, 0xf);
    DPP_MAX_STEP(a, 0x114, 0xf);  DPP_MAX_STEP(b, 0x114, 0xf);
    DPP_MAX_STEP(a, 0x118, 0xf);  DPP_MAX_STEP(b, 0x118, 0xf);
    DPP_MAX_STEP(a, 0x142, 0xa);  DPP_MAX_STEP(b, 0x142, 0xa);
    DPP_MAX_STEP(a, 0x143, 0xc);  DPP_MAX_STEP(b, 0x143, 0xc);
    a = __builtin_bit_cast(float,
        __builtin_amdgcn_readlane(__builtin_bit_cast(int, a), 63));
    b = __builtin_bit_cast(float,
        __builtin_amdgcn_readlane(__builtin_bit_cast(int, b), 63));
}

// One recurrence step for one v2f unit. Fast tier: deg-2 Taylor (3 v2f).
// Slow tier (~3.5 of 5 units/iter, measured via R7 attribution probe):
// exact exp/log form e *= (1-y)^k = exp2(k*log2(1-y)) — 4 VALU slots +
// 4 trans ops, replacing the 28-slot polynomial (R6 proved the math
// passes applied everywhere; here it's gated to active units only).
__device__ __forceinline__ void unit_step(v2f& e2u, float rs, float a, float b,
                                          float thr, v2f& ns) {
    constexpr float KPOW = 100.0f / 7.0f;
    const v2f K1 = {1.0f, 1.0f};
    v2f e = e2u;
    if (__builtin_expect(__any(fmaxf(e.x, e.y) > thr), 0)) {
        v2f rsv = {rs, rs};
        v2f y = e * rsv;
        float fx = fmaxf(1.0f - y.x, 1e-35f);
        float fy = fmaxf(1.0f - y.y, 1e-35f);
        float gx = __builtin_amdgcn_exp2f(KPOW * __builtin_amdgcn_logf(fx));
        float gy = __builtin_amdgcn_exp2f(KPOW * __builtin_amdgcn_logf(fy));
        e.x *= gx;
        e.y *= gy;
    } else {
        v2f av = {a, a}, bv = {b, b};
        v2f p = __builtin_elementwise_fma(bv, e, av);
        p = __builtin_elementwise_fma(p, e, K1);
        e *= p;
    }
    e2u = e;
    ns += e;
}

// 4 blocks/CU (16 waves/CU); VGPR cap 128.
__global__ __launch_bounds__(BLOCK, 4) void dimmask_kernel(
    const float* __restrict__ x, const float* __restrict__ W1,
    const float* __restrict__ b1, const float* __restrict__ W2,
    const float* __restrict__ b2, float* __restrict__ out)
{
    constexpr float INV_T = 1.0f / 0.07f;
    constexpr float LOG2E = 1.4426950408889634f;
    constexpr float TEMP  = 0.07f;

    __shared__ float lds_a[ROWS][D];          // x rows, then ht
    __shared__ float lds_part[4][ROWS][HID];
    __shared__ float lds_hid[ROWS][HID];

    const int tid  = threadIdx.x;
    const int row0 = blockIdx.x * ROWS;

    // ---- stage x rows into LDS (coalesced float4) ----
    {
        const float4* xv  = (const float4*)(x + (size_t)row0 * D);
        float4*       lxv = (float4*)(&lds_a[0][0]);
        for (int i = tid; i < ROWS * D / 4; i += BLOCK) lxv[i] = xv[i];
    }
    __syncthreads();

    // ---- GEMM1: hid[r][k] = relu(sum_t x[r][t]*W1[t][k] + b1[k]) ----
    {
        const int k = tid & 63, c = tid >> 6;
        float acc[ROWS];
#pragma unroll
        for (int r = 0; r < ROWS; ++r) acc[r] = 0.f;
        const int q0 = c * 40;                 // float4 index base (c*160/4)
#pragma unroll 2
        for (int q = q0; q < q0 + 40; ++q) {
            const int tb = q * 4;
            float w0 = W1[(tb + 0) * HID + k];
            float w1 = W1[(tb + 1) * HID + k];
            float w2 = W1[(tb + 2) * HID + k];
            float w3 = W1[(tb + 3) * HID + k];
#pragma unroll
            for (int r = 0; r < ROWS; ++r) {
                float4 xa = ((const float4*)&lds_a[r][0])[q];
                acc[r] += xa.x * w0 + xa.y * w1 + xa.z * w2 + xa.w * w3;
            }
        }
#pragma unroll
        for (int r = 0; r < ROWS; ++r) lds_part[c][r][k] = acc[r];
    }
    __syncthreads();
    for (int idx = tid; idx < ROWS * HID; idx += BLOCK) {
        const int r = idx >> 6, k = idx & 63;
        float s = lds_part[0][r][k] + lds_part[1][r][k]
                + lds_part[2][r][k] + lds_part[3][r][k] + b1[k];
        lds_hid[r][k] = fmaxf(s, 0.f);
    }
    __syncthreads();

    // ---- GEMM2: ht[r][j] = -h*log2e/T over dead x in lds_a ----
    for (int j = tid; j < D; j += BLOCK) {
        float acc[ROWS];
#pragma unroll
        for (int r = 0; r < ROWS; ++r) acc[r] = 0.f;
#pragma unroll 2
        for (int k4 = 0; k4 < HID / 4; ++k4) {
            const int kb = k4 * 4;
            float w0 = W2[(kb + 0) * D + j];
            float w1 = W2[(kb + 1) * D + j];
            float w2 = W2[(kb + 2) * D + j];
            float w3 = W2[(kb + 3) * D + j];
#pragma unroll
            for (int r = 0; r < ROWS; ++r) {
                float4 hh = ((const float4*)&lds_hid[r][0])[k4];
                acc[r] += hh.x * w0 + hh.y * w1 + hh.z * w2 + hh.w * w3;
            }
        }
        float bb = b2[j];
#pragma unroll
        for (int r = 0; r < ROWS; ++r)
            lds_a[r][j] = -(acc[r] + bb) * (LOG2E * INV_T);
    }
    __syncthreads();

    // ---- Phase B: one wave per TWO rows; packed f32 e-domain recurrence ----
    const int w = tid >> 6, l = tid & 63;
    const int rA = 2 * w, rB = 2 * w + 1;
    v2f eA[5], eB[5];
    float hmaxA, hmaxB;
    {
        float htA[10], htB[10];
        float ha = -3.0e38f, hb = -3.0e38f;
#pragma unroll
        for (int u = 0; u < 10; ++u) {
            htA[u] = lds_a[rA][l + 64 * u];
            htB[u] = lds_a[rB][l + 64 * u];
            ha = fmaxf(ha, htA[u]);
            hb = fmaxf(hb, htB[u]);
        }
        wave_max_dpp2(ha, hb);
        hmaxA = ha; hmaxB = hb;
#pragma unroll
        for (int u = 0; u < 5; ++u) {
            eA[u].x = __builtin_amdgcn_exp2f(fmaxf(htA[2 * u]     - ha, -80.f));
            eA[u].y = __builtin_amdgcn_exp2f(fmaxf(htA[2 * u + 1] - ha, -80.f));
            eB[u].x = __builtin_amdgcn_exp2f(fmaxf(htB[2 * u]     - hb, -80.f));
            eB[u].y = __builtin_amdgcn_exp2f(fmaxf(htB[2 * u + 1] - hb, -80.f));
        }
    }

    v2f saccA = (eA[0] + eA[1]) + ((eA[2] + eA[3]) + eA[4]);
    v2f saccB = (eB[0] + eB[1]) + ((eB[2] + eB[3]) + eB[4]);

    for (int it = 0; it < NITER; ++it) {
        float sA = saccA.x + saccA.y;
        float sB = saccB.x + saccB.y;
        wave_sum_dpp2(sA, sB);
        float rsA = __builtin_amdgcn_rcpf(sA);
        float rsB = __builtin_amdgcn_rcpf(sB);
        float aA = -14.2857143f * rsA, bA = (94.8979592f * rsA) * rsA;
        float aB = -14.2857143f * rsB, bB = (94.8979592f * rsB) * rsB;
        float thrA = 0.02f * sA, thrB = 0.02f * sB;
        v2f nsA = {0.f, 0.f}, nsB = {0.f, 0.f};
#pragma unroll
        for (int u = 0; u < 5; ++u) {
            unit_step(eA[u], rsA, aA, bA, thrA, nsA);
            unit_step(eB[u], rsB, aB, bB, thrB, nsB);
        }
        saccA = nsA; saccB = nsB;
    }

    // ---- epilogue: m = (e/E)^T = exp2(T*(log2(e) - c)), c = clamp(ht-hmax) ----
#pragma unroll
    for (int pr = 0; pr < 2; ++pr) {
        const int r = (pr == 0) ? rA : rB;
        const float hm = (pr == 0) ? hmaxA : hmaxB;
        v2f* e2 = (pr == 0) ? eA : eB;
        const float* xrow = x + (size_t)(row0 + r) * D;
        float* orow = out + (size_t)(row0 + r) * D;
#pragma unroll
        for (int u = 0; u < 5; ++u) {
            const int j0 = l + 128 * u, j1 = j0 + 64;
            float c0 = fmaxf(lds_a[r][j0] - hm, -80.f);
            float c1 = fmaxf(lds_a[r][j1] - hm, -80.f);
            float m0 = __builtin_amdgcn_exp2f(
                TEMP * (__builtin_amdgcn_logf(e2[u].x) - c0));
            float m1 = __builtin_amdgcn_exp2f(
                TEMP * (__builtin_amdgcn_logf(e2[u].y) - c1));
            orow[j0] = m0 * xrow[j0];
            orow[j1] = m1 * xrow[j1];
        }
    }
}

extern "C" void kernel_launch(void* const* d_in, const int* in_sizes, int n_in,
                              void* d_out, int out_size, void* d_ws, size_t ws_size,
                              hipStream_t stream) {
    const float* x  = (const float*)d_in[0];
    const float* W1 = (const float*)d_in[1];
    const float* b1 = (const float*)d_in[2];
    const float* W2 = (const float*)d_in[3];
    const float* b2 = (const float*)d_in[4];
    float* out = (float*)d_out;

    const int B = in_sizes[0] / D;            // 8192
    dim3 grid(B / ROWS), block(BLOCK);
    hipLaunchKernelGGL(dimmask_kernel, grid, block, 0, stream, x, W1, b1, W2, b2, out);
}

// Round 11
// 182.196 us; speedup vs baseline: 1.3907x; 1.0027x over previous
//
#include <hip/hip_runtime.h>

#define D 640
#define HID 64
#define NITER 64
#define ROWS 8           // rows per block; each of 4 waves owns 2 rows
#define BLOCK 256

typedef float v2f __attribute__((ext_vector_type(2)));

// ---- DPP wave64 reductions (VALU pipe only) ----
#define DPP_ADD_STEP(v, ctrl, rmask)                                          \
    v += __builtin_bit_cast(float, __builtin_amdgcn_update_dpp(               \
             0, __builtin_bit_cast(int, v), ctrl, rmask, 0xf, true))
#define DPP_MAX_STEP(v, ctrl, rmask)                                          \
    v = fmaxf(v, __builtin_bit_cast(float, __builtin_amdgcn_update_dpp(       \
             __builtin_bit_cast(int, v), __builtin_bit_cast(int, v),          \
             ctrl, rmask, 0xf, false)))

// Two interleaved reduce chains (rows A and B) -> 2x ILP on the serial path.
__device__ __forceinline__ void wave_sum_dpp2(float& a, float& b) {
    DPP_ADD_STEP(a, 0x111, 0xf);  DPP_ADD_STEP(b, 0x111, 0xf);
    DPP_ADD_STEP(a, 0x112, 0xf);  DPP_ADD_STEP(b, 0x112, 0xf);
    DPP_ADD_STEP(a, 0x114, 0xf);  DPP_ADD_STEP(b, 0x114, 0xf);
    DPP_ADD_STEP(a, 0x118, 0xf);  DPP_ADD_STEP(b, 0x118, 0xf);
    DPP_ADD_STEP(a, 0x142, 0xa);  DPP_ADD_STEP(b, 0x142, 0xa);
    DPP_ADD_STEP(a, 0x143, 0xc);  DPP_ADD_STEP(b, 0x143, 0xc);
    a = __builtin_bit_cast(float,
        __builtin_amdgcn_readlane(__builtin_bit_cast(int, a), 63));
    b = __builtin_bit_cast(float,
        __builtin_amdgcn_readlane(__builtin_bit_cast(int, b), 63));
}
__device__ __forceinline__ void wave_max_dpp2(float& a, float& b) {
    DPP_MAX_STEP(a, 0x111, 0xf);  DPP_MAX_STEP(b, 0x111, 0xf);
    DPP_MAX_STEP(a, 0x112, 0xf);  DPP_MAX_STEP(b, 0x112, 0xf);
    DPP_MAX_STEP(a, 0x114, 0xf);  DPP_MAX_STEP(b, 0x114, 0xf);
    DPP_MAX_STEP(a, 0x118, 0xf);  DPP_MAX_STEP(b, 0x118, 0xf);
    DPP_MAX_STEP(a, 0x142, 0xa);  DPP_MAX_STEP(b, 0x142, 0xa);
    DPP_MAX_STEP(a, 0x143, 0xc);  DPP_MAX_STEP(b, 0x143, 0xc);
    a = __builtin_bit_cast(float,
        __builtin_amdgcn_readlane(__builtin_bit_cast(int, a), 63));
    b = __builtin_bit_cast(float,
        __builtin_amdgcn_readlane(__builtin_bit_cast(int, b), 63));
}

// One recurrence step for one v2f unit. Fast tier: deg-2 Taylor (3 v2f).
// Slow tier: exact exp/log form e *= (1-y)^k = exp2(k*log2(1-y)).
__device__ __forceinline__ void unit_step(v2f& e2u, float rs, float a, float b,
                                          float thr, v2f& ns) {
    constexpr float KPOW = 100.0f / 7.0f;
    const v2f K1 = {1.0f, 1.0f};
    v2f e = e2u;
    if (__builtin_expect(__any(fmaxf(e.x, e.y) > thr), 0)) {
        v2f rsv = {rs, rs};
        v2f y = e * rsv;
        float fx = fmaxf(1.0f - y.x, 1e-35f);
        float fy = fmaxf(1.0f - y.y, 1e-35f);
        float gx = __builtin_amdgcn_exp2f(KPOW * __builtin_amdgcn_logf(fx));
        float gy = __builtin_amdgcn_exp2f(KPOW * __builtin_amdgcn_logf(fy));
        e.x *= gx;
        e.y *= gy;
    } else {
        v2f av = {a, a}, bv = {b, b};
        v2f p = __builtin_elementwise_fma(bv, e, av);
        p = __builtin_elementwise_fma(p, e, K1);
        e *= p;
    }
    e2u = e;
    ns += e;
}

// 4 blocks/CU (16 waves/CU); VGPR cap 128.
__global__ __launch_bounds__(BLOCK, 4) void dimmask_kernel(
    const float* __restrict__ x, const float* __restrict__ W1,
    const float* __restrict__ b1, const float* __restrict__ W2,
    const float* __restrict__ b2, float* __restrict__ out)
{
    constexpr float INV_T = 1.0f / 0.07f;
    constexpr float LOG2E = 1.4426950408889634f;
    constexpr float TEMP  = 0.07f;

    __shared__ float lds_a[ROWS][D];          // x rows, then ht
    __shared__ float lds_part[4][ROWS][HID];
    __shared__ float lds_hid[ROWS][HID];

    const int tid  = threadIdx.x;
    const int row0 = blockIdx.x * ROWS;

    // ---- stage x rows into LDS (coalesced float4) ----
    {
        const float4* xv  = (const float4*)(x + (size_t)row0 * D);
        float4*       lxv = (float4*)(&lds_a[0][0]);
        for (int i = tid; i < ROWS * D / 4; i += BLOCK) lxv[i] = xv[i];
    }
    __syncthreads();

    // ---- GEMM1: hid[r][k] = relu(sum_t x[r][t]*W1[t][k] + b1[k]) ----
    {
        const int k = tid & 63, c = tid >> 6;
        float acc[ROWS];
#pragma unroll
        for (int r = 0; r < ROWS; ++r) acc[r] = 0.f;
        const int q0 = c * 40;                 // float4 index base (c*160/4)
#pragma unroll 2
        for (int q = q0; q < q0 + 40; ++q) {
            const int tb = q * 4;
            float w0 = W1[(tb + 0) * HID + k];
            float w1 = W1[(tb + 1) * HID + k];
            float w2 = W1[(tb + 2) * HID + k];
            float w3 = W1[(tb + 3) * HID + k];
#pragma unroll
            for (int r = 0; r < ROWS; ++r) {
                float4 xa = ((const float4*)&lds_a[r][0])[q];
                acc[r] += xa.x * w0 + xa.y * w1 + xa.z * w2 + xa.w * w3;
            }
        }
#pragma unroll
        for (int r = 0; r < ROWS; ++r) lds_part[c][r][k] = acc[r];
    }
    __syncthreads();
    for (int idx = tid; idx < ROWS * HID; idx += BLOCK) {
        const int r = idx >> 6, k = idx & 63;
        float s = lds_part[0][r][k] + lds_part[1][r][k]
                + lds_part[2][r][k] + lds_part[3][r][k] + b1[k];
        lds_hid[r][k] = fmaxf(s, 0.f);
    }
    __syncthreads();

    // ---- GEMM2: ht[r][j] = -h*log2e/T over dead x in lds_a ----
    for (int j = tid; j < D; j += BLOCK) {
        float acc[ROWS];
#pragma unroll
        for (int r = 0; r < ROWS; ++r) acc[r] = 0.f;
#pragma unroll 2
        for (int k4 = 0; k4 < HID / 4; ++k4) {
            const int kb = k4 * 4;
            float w0 = W2[(kb + 0) * D + j];
            float w1 = W2[(kb + 1) * D + j];
            float w2 = W2[(kb + 2) * D + j];
            float w3 = W2[(kb + 3) * D + j];
#pragma unroll
            for (int r = 0; r < ROWS; ++r) {
                float4 hh = ((const float4*)&lds_hid[r][0])[k4];
                acc[r] += hh.x * w0 + hh.y * w1 + hh.z * w2 + hh.w * w3;
            }
        }
        float bb = b2[j];
#pragma unroll
        for (int r = 0; r < ROWS; ++r)
            lds_a[r][j] = -(acc[r] + bb) * (LOG2E * INV_T);
    }
    __syncthreads();

    // ---- Phase B: one wave per TWO rows; packed f32 e-domain recurrence ----
    const int w = tid >> 6, l = tid & 63;
    const int rA = 2 * w, rB = 2 * w + 1;
    v2f eA[5], eB[5];
    float hmaxA, hmaxB;
    {
        float htA[10], htB[10];
        float ha = -3.0e38f, hb = -3.0e38f;
#pragma unroll
        for (int u = 0; u < 10; ++u) {
            htA[u] = lds_a[rA][l + 64 * u];
            htB[u] = lds_a[rB][l + 64 * u];
            ha = fmaxf(ha, htA[u]);
            hb = fmaxf(hb, htB[u]);
        }
        wave_max_dpp2(ha, hb);
        hmaxA = ha; hmaxB = hb;
#pragma unroll
        for (int u = 0; u < 5; ++u) {
            eA[u].x = __builtin_amdgcn_exp2f(fmaxf(htA[2 * u]     - ha, -80.f));
            eA[u].y = __builtin_amdgcn_exp2f(fmaxf(htA[2 * u + 1] - ha, -80.f));
            eB[u].x = __builtin_amdgcn_exp2f(fmaxf(htB[2 * u]     - hb, -80.f));
            eB[u].y = __builtin_amdgcn_exp2f(fmaxf(htB[2 * u + 1] - hb, -80.f));
        }
    }

    // ==== DE-PHASE: break wave lockstep so latency stalls interleave ====
    // All waves enter Phase B from the same barrier with identical code ->
    // identical timing -> every wave stalls on its DPP-reduce chain in the
    // same cycles, so co-resident waves never hide each other's latency
    // (R1 8-wave == R2 4-wave == 130us invariance; R7 probe: zero overlap).
    // Stagger wave starts by ~1/4..3/4 of one ~385-cyc iteration.
    // s_sleep is semantically inert; emitted as raw asm (not the builtin)
    // in case the builtin was implicated in the R9/R10 bench failures.
    if      (w == 1) asm volatile("s_sleep 2");   // ~128 cyc
    else if (w == 2) asm volatile("s_sleep 3");   // ~192 cyc
    else if (w == 3) asm volatile("s_sleep 5");   // ~320 cyc

    v2f saccA = (eA[0] + eA[1]) + ((eA[2] + eA[3]) + eA[4]);
    v2f saccB = (eB[0] + eB[1]) + ((eB[2] + eB[3]) + eB[4]);

    for (int it = 0; it < NITER; ++it) {
        float sA = saccA.x + saccA.y;
        float sB = saccB.x + saccB.y;
        wave_sum_dpp2(sA, sB);
        float rsA = __builtin_amdgcn_rcpf(sA);
        float rsB = __builtin_amdgcn_rcpf(sB);
        float aA = -14.2857143f * rsA, bA = (94.8979592f * rsA) * rsA;
        float aB = -14.2857143f * rsB, bB = (94.8979592f * rsB) * rsB;
        float thrA = 0.02f * sA, thrB = 0.02f * sB;
        v2f nsA = {0.f, 0.f}, nsB = {0.f, 0.f};
#pragma unroll
        for (int u = 0; u < 5; ++u) {
            unit_step(eA[u], rsA, aA, bA, thrA, nsA);
            unit_step(eB[u], rsB, aB, bB, thrB, nsB);
        }
        saccA = nsA; saccB = nsB;
    }

    // ---- epilogue: m = (e/E)^T = exp2(T*(log2(e) - c)), c = clamp(ht-hmax) ----
#pragma unroll
    for (int pr = 0; pr < 2; ++pr) {
        const int r = (pr == 0) ? rA : rB;
        const float hm = (pr == 0) ? hmaxA : hmaxB;
        v2f* e2 = (pr == 0) ? eA : eB;
        const float* xrow = x + (size_t)(row0 + r) * D;
        float* orow = out + (size_t)(row0 + r) * D;
#pragma unroll
        for (int u = 0; u < 5; ++u) {
            const int j0 = l + 128 * u, j1 = j0 + 64;
            float c0 = fmaxf(lds_a[r][j0] - hm, -80.f);
            float c1 = fmaxf(lds_a[r][j1] - hm, -80.f);
            float m0 = __builtin_amdgcn_exp2f(
                TEMP * (__builtin_amdgcn_logf(e2[u].x) - c0));
            float m1 = __builtin_amdgcn_exp2f(
                TEMP * (__builtin_amdgcn_logf(e2[u].y) - c1));
            orow[j0] = m0 * xrow[j0];
            orow[j1] = m1 * xrow[j1];
        }
    }
}

extern "C" void kernel_launch(void* const* d_in, const int* in_sizes, int n_in,
                              void* d_out, int out_size, void* d_ws, size_t ws_size,
                              hipStream_t stream) {
    const float* x  = (const float*)d_in[0];
    const float* W1 = (const float*)d_in[1];
    const float* b1 = (const float*)d_in[2];
    const float* W2 = (const float*)d_in[3];
    const float* b2 = (const float*)d_in[4];
    float* out = (float*)d_out;

    const int B = in_sizes[0] / D;            // 8192
    dim3 grid(B / ROWS), block(BLOCK);
    hipLaunchKernelGGL(dimmask_kernel, grid, block, 0, stream, x, W1, b1, W2, b2, out);
}

// Round 12
// 180.476 us; speedup vs baseline: 1.4040x; 1.0095x over previous
//
#include <hip/hip_runtime.h>

#define D 640
#define HID 64
#define NITER 64
#define ROWS 8           // rows per block; each of 4 waves owns 2 rows
#define BLOCK 256

typedef float v2f __attribute__((ext_vector_type(2)));

// ---- DPP wave64 reduction pieces (VALU pipe only) ----
#define DPP_ADD_STEP(v, ctrl, rmask)                                          \
    v += __builtin_bit_cast(float, __builtin_amdgcn_update_dpp(               \
             0, __builtin_bit_cast(int, v), ctrl, rmask, 0xf, true))
#define DPP_MAX_STEP(v, ctrl, rmask)                                          \
    v = fmaxf(v, __builtin_bit_cast(float, __builtin_amdgcn_update_dpp(       \
             __builtin_bit_cast(int, v), __builtin_bit_cast(int, v),          \
             ctrl, rmask, 0xf, false)))

// Issue-only sum chain: 6 dependent DPP adds, result lands in lane 63.
// readlane is deliberately SEPARATE so the chain can be issued early
// (end of producing phase) and consumed late (start of next iteration),
// with independent work scheduled into its cross-lane latency gaps.
__device__ __forceinline__ float dpp_chain_sum(float v) {
    DPP_ADD_STEP(v, 0x111, 0xf);  // row_shr:1
    DPP_ADD_STEP(v, 0x112, 0xf);  // row_shr:2
    DPP_ADD_STEP(v, 0x114, 0xf);  // row_shr:4
    DPP_ADD_STEP(v, 0x118, 0xf);  // row_shr:8
    DPP_ADD_STEP(v, 0x142, 0xa);  // row_bcast:15
    DPP_ADD_STEP(v, 0x143, 0xc);  // row_bcast:31
    return v;
}
__device__ __forceinline__ float lane63(float v) {
    return __builtin_bit_cast(float,
        __builtin_amdgcn_readlane(__builtin_bit_cast(int, v), 63));
}

__device__ __forceinline__ void wave_max_dpp2(float& a, float& b) {
    DPP_MAX_STEP(a, 0x111, 0xf);  DPP_MAX_STEP(b, 0x111, 0xf);
    DPP_MAX_STEP(a, 0x112, 0xf);  DPP_MAX_STEP(b, 0x112, 0xf);
    DPP_MAX_STEP(a, 0x114, 0xf);  DPP_MAX_STEP(b, 0x114, 0xf);
    DPP_MAX_STEP(a, 0x118, 0xf);  DPP_MAX_STEP(b, 0x118, 0xf);
    DPP_MAX_STEP(a, 0x142, 0xa);  DPP_MAX_STEP(b, 0x142, 0xa);
    DPP_MAX_STEP(a, 0x143, 0xc);  DPP_MAX_STEP(b, 0x143, 0xc);
    a = lane63(a);
    b = lane63(b);
}

// One recurrence step for one v2f unit (R8 math, measured-good, unchanged).
__device__ __forceinline__ void unit_step(v2f& e2u, float rs, float a, float b,
                                          float thr, v2f& ns) {
    constexpr float KPOW = 100.0f / 7.0f;
    const v2f K1 = {1.0f, 1.0f};
    v2f e = e2u;
    if (__builtin_expect(__any(fmaxf(e.x, e.y) > thr), 0)) {
        v2f rsv = {rs, rs};
        v2f y = e * rsv;
        float fx = fmaxf(1.0f - y.x, 1e-35f);
        float fy = fmaxf(1.0f - y.y, 1e-35f);
        float gx = __builtin_amdgcn_exp2f(KPOW * __builtin_amdgcn_logf(fx));
        float gy = __builtin_amdgcn_exp2f(KPOW * __builtin_amdgcn_logf(fy));
        e.x *= gx;
        e.y *= gy;
    } else {
        v2f av = {a, a}, bv = {b, b};
        v2f p = __builtin_elementwise_fma(bv, e, av);
        p = __builtin_elementwise_fma(p, e, K1);
        e *= p;
    }
    e2u = e;
    ns += e;
}

// 4 blocks/CU (16 waves/CU); VGPR cap 128.
__global__ __launch_bounds__(BLOCK, 4) void dimmask_kernel(
    const float* __restrict__ x, const float* __restrict__ W1,
    const float* __restrict__ b1, const float* __restrict__ W2,
    const float* __restrict__ b2, float* __restrict__ out)
{
    constexpr float INV_T = 1.0f / 0.07f;
    constexpr float LOG2E = 1.4426950408889634f;
    constexpr float TEMP  = 0.07f;

    __shared__ float lds_a[ROWS][D];          // x rows, then ht
    __shared__ float lds_part[4][ROWS][HID];
    __shared__ float lds_hid[ROWS][HID];

    const int tid  = threadIdx.x;
    const int row0 = blockIdx.x * ROWS;

    // ---- stage x rows into LDS (coalesced float4) ----
    {
        const float4* xv  = (const float4*)(x + (size_t)row0 * D);
        float4*       lxv = (float4*)(&lds_a[0][0]);
        for (int i = tid; i < ROWS * D / 4; i += BLOCK) lxv[i] = xv[i];
    }
    __syncthreads();

    // ---- GEMM1: hid[r][k] = relu(sum_t x[r][t]*W1[t][k] + b1[k]) ----
    {
        const int k = tid & 63, c = tid >> 6;
        float acc[ROWS];
#pragma unroll
        for (int r = 0; r < ROWS; ++r) acc[r] = 0.f;
        const int q0 = c * 40;                 // float4 index base (c*160/4)
#pragma unroll 2
        for (int q = q0; q < q0 + 40; ++q) {
            const int tb = q * 4;
            float w0 = W1[(tb + 0) * HID + k];
            float w1 = W1[(tb + 1) * HID + k];
            float w2 = W1[(tb + 2) * HID + k];
            float w3 = W1[(tb + 3) * HID + k];
#pragma unroll
            for (int r = 0; r < ROWS; ++r) {
                float4 xa = ((const float4*)&lds_a[r][0])[q];
                acc[r] += xa.x * w0 + xa.y * w1 + xa.z * w2 + xa.w * w3;
            }
        }
#pragma unroll
        for (int r = 0; r < ROWS; ++r) lds_part[c][r][k] = acc[r];
    }
    __syncthreads();
    for (int idx = tid; idx < ROWS * HID; idx += BLOCK) {
        const int r = idx >> 6, k = idx & 63;
        float s = lds_part[0][r][k] + lds_part[1][r][k]
                + lds_part[2][r][k] + lds_part[3][r][k] + b1[k];
        lds_hid[r][k] = fmaxf(s, 0.f);
    }
    __syncthreads();

    // ---- GEMM2: ht[r][j] = -h*log2e/T over dead x in lds_a ----
    for (int j = tid; j < D; j += BLOCK) {
        float acc[ROWS];
#pragma unroll
        for (int r = 0; r < ROWS; ++r) acc[r] = 0.f;
#pragma unroll 2
        for (int k4 = 0; k4 < HID / 4; ++k4) {
            const int kb = k4 * 4;
            float w0 = W2[(kb + 0) * D + j];
            float w1 = W2[(kb + 1) * D + j];
            float w2 = W2[(kb + 2) * D + j];
            float w3 = W2[(kb + 3) * D + j];
#pragma unroll
            for (int r = 0; r < ROWS; ++r) {
                float4 hh = ((const float4*)&lds_hid[r][0])[k4];
                acc[r] += hh.x * w0 + hh.y * w1 + hh.z * w2 + hh.w * w3;
            }
        }
        float bb = b2[j];
#pragma unroll
        for (int r = 0; r < ROWS; ++r)
            lds_a[r][j] = -(acc[r] + bb) * (LOG2E * INV_T);
    }
    __syncthreads();

    // ---- Phase B: one wave per TWO rows; ANTIPHASE software pipeline ----
    // Old order: [chainA||chainB] -> readlanes -> updates. All updates
    // depend on the readlanes, so NOTHING in-wave fills the ~12 serial
    // cross-lane DPP latencies (the unattributed ~60% of Phase B time).
    // New order per iter:
    //   readlaneA -> updateA -> chainA -> readlaneB -> updateB -> chainB
    // Each chain's consumption is one full update-block away from its
    // issue, giving the scheduler independent instructions to splice
    // into every DPP gap. Per-row arithmetic is bit-identical.
    const int w = tid >> 6, l = tid & 63;
    const int rA = 2 * w, rB = 2 * w + 1;
    v2f eA[5], eB[5];
    float hmaxA, hmaxB;
    {
        float htA[10], htB[10];
        float ha = -3.0e38f, hb = -3.0e38f;
#pragma unroll
        for (int u = 0; u < 10; ++u) {
            htA[u] = lds_a[rA][l + 64 * u];
            htB[u] = lds_a[rB][l + 64 * u];
            ha = fmaxf(ha, htA[u]);
            hb = fmaxf(hb, htB[u]);
        }
        wave_max_dpp2(ha, hb);
        hmaxA = ha; hmaxB = hb;
#pragma unroll
        for (int u = 0; u < 5; ++u) {
            eA[u].x = __builtin_amdgcn_exp2f(fmaxf(htA[2 * u]     - ha, -80.f));
            eA[u].y = __builtin_amdgcn_exp2f(fmaxf(htA[2 * u + 1] - ha, -80.f));
            eB[u].x = __builtin_amdgcn_exp2f(fmaxf(htB[2 * u]     - hb, -80.f));
            eB[u].y = __builtin_amdgcn_exp2f(fmaxf(htB[2 * u + 1] - hb, -80.f));
        }
    }

    v2f saccA = (eA[0] + eA[1]) + ((eA[2] + eA[3]) + eA[4]);
    v2f saccB = (eB[0] + eB[1]) + ((eB[2] + eB[3]) + eB[4]);

    // prologue: issue both initial chains
    float chA = dpp_chain_sum(saccA.x + saccA.y);
    float chB = dpp_chain_sum(saccB.x + saccB.y);

    for (int it = 0; it < NITER; ++it) {
        // ---- row A: consume chainA, update, re-issue chainA ----
        float sA  = lane63(chA);
        float rsA = __builtin_amdgcn_rcpf(sA);
        float aA = -14.2857143f * rsA, bA = (94.8979592f * rsA) * rsA;
        float thrA = 0.02f * sA;
        v2f nsA = {0.f, 0.f};
#pragma unroll
        for (int u = 0; u < 5; ++u) unit_step(eA[u], rsA, aA, bA, thrA, nsA);
        chA = dpp_chain_sum(nsA.x + nsA.y);   // latency covered by row B below

        // ---- row B: consume chainB, update, re-issue chainB ----
        float sB  = lane63(chB);
        float rsB = __builtin_amdgcn_rcpf(sB);
        float aB = -14.2857143f * rsB, bB = (94.8979592f * rsB) * rsB;
        float thrB = 0.02f * sB;
        v2f nsB = {0.f, 0.f};
#pragma unroll
        for (int u = 0; u < 5; ++u) unit_step(eB[u], rsB, aB, bB, thrB, nsB);
        chB = dpp_chain_sum(nsB.x + nsB.y);   // latency covered by next-iter row A
    }

    // ---- epilogue: m = (e/E)^T = exp2(T*(log2(e) - c)), c = clamp(ht-hmax) ----
#pragma unroll
    for (int pr = 0; pr < 2; ++pr) {
        const int r = (pr == 0) ? rA : rB;
        const float hm = (pr == 0) ? hmaxA : hmaxB;
        v2f* e2 = (pr == 0) ? eA : eB;
        const float* xrow = x + (size_t)(row0 + r) * D;
        float* orow = out + (size_t)(row0 + r) * D;
#pragma unroll
        for (int u = 0; u < 5; ++u) {
            const int j0 = l + 128 * u, j1 = j0 + 64;
            float c0 = fmaxf(lds_a[r][j0] - hm, -80.f);
            float c1 = fmaxf(lds_a[r][j1] - hm, -80.f);
            float m0 = __builtin_amdgcn_exp2f(
                TEMP * (__builtin_amdgcn_logf(e2[u].x) - c0));
            float m1 = __builtin_amdgcn_exp2f(
                TEMP * (__builtin_amdgcn_logf(e2[u].y) - c1));
            orow[j0] = m0 * xrow[j0];
            orow[j1] = m1 * xrow[j1];
        }
    }
}

extern "C" void kernel_launch(void* const* d_in, const int* in_sizes, int n_in,
                              void* d_out, int out_size, void* d_ws, size_t ws_size,
                              hipStream_t stream) {
    const float* x  = (const float*)d_in[0];
    const float* W1 = (const float*)d_in[1];
    const float* b1 = (const float*)d_in[2];
    const float* W2 = (const float*)d_in[3];
    const float* b2 = (const float*)d_in[4];
    float* out = (float*)d_out;

    const int B = in_sizes[0] / D;            // 8192
    dim3 grid(B / ROWS), block(BLOCK);
    hipLaunchKernelGGL(dimmask_kernel, grid, block, 0, stream, x, W1, b1, W2, b2, out);
}